// Round 5
// baseline (413.371 us; speedup 1.0000x reference)
//
#include <hip/hip_runtime.h>

#define W_IMG 1024
#define H_IMG 1024
#define HW_IMG (W_IMG * H_IMG)
#define NV 1000000
#define NE 3000000
#define MAX_DEPTH 10.0f
#define CREGU 2000.0f

// ---- single-u64-per-edge fixed-point packing ----
// layout (LSB..MSB): cnt:6 | z:18 | y:20 | x:20
#define SXY 65536.0f
#define INV_SXY 1.52587890625e-5f
#define SZ 16384.0f
#define INV_SZ 6.103515625e-5f
#define BXY 8192
#define BZ 2048

__device__ __forceinline__ unsigned long long pack_dv(float x, float y, float z) {
    x = fminf(fmaxf(x, -0.12f), 0.12f);
    y = fminf(fmaxf(y, -0.12f), 0.12f);
    z = fminf(fmaxf(z, -0.12f), 0.12f);
    unsigned long long px = (unsigned)((int)rintf(x * SXY) + BXY);
    unsigned long long py = (unsigned)((int)rintf(y * SXY) + BXY);
    unsigned long long pz = (unsigned)((int)rintf(z * SZ) + BZ);
    return (px << 44) | (py << 24) | (pz << 6) | 1ull;
}

__device__ __forceinline__ float block_sum_256(float v, float* smem) {
#pragma unroll
    for (int o = 32; o > 0; o >>= 1) v += __shfl_down(v, o, 64);
    int lane = threadIdx.x & 63;
    int wid  = threadIdx.x >> 6;
    if (lane == 0) smem[wid] = v;
    __syncthreads();
    float r = 0.f;
    if (threadIdx.x == 0) r = smem[0] + smem[1] + smem[2] + smem[3];
    __syncthreads();
    return r;  // valid on thread 0 only
}

__global__ void k_init(unsigned* depth_bits, unsigned long long* neigh,
                       float* sums, float* out) {
    int i = blockIdx.x * blockDim.x + threadIdx.x;
    int stride = gridDim.x * blockDim.x;
    for (int j = i; j < HW_IMG; j += stride) depth_bits[j] = 0x41200000u;  // 10.0f
    for (int j = i; j < NV; j += stride) neigh[j] = 0ull;
    if (i == 0) {
        sums[0] = 0.f; sums[1] = 0.f; sums[2] = 0.f;
        out[0] = 0.f;
    }
}

// vertex sums (for mean) + packed dv
__global__ void k_sum_dv(const float* __restrict__ verts,
                         const float* __restrict__ verts_ref,
                         unsigned long long* __restrict__ pdv, float* sums) {
    __shared__ float smem[4];
    int i = blockIdx.x * blockDim.x + threadIdx.x;
    int stride = gridDim.x * blockDim.x;
    float sx = 0.f, sy = 0.f, sz = 0.f;
    for (int j = i; j < NV; j += stride) {
        float x = verts[3 * j + 0];
        float y = verts[3 * j + 1];
        float z = verts[3 * j + 2];
        sx += x; sy += y; sz += z;
        pdv[j] = pack_dv(x - verts_ref[3 * j + 0],
                         y - verts_ref[3 * j + 1],
                         z - verts_ref[3 * j + 2]);
    }
    float bx = block_sum_256(sx, smem);
    float by = block_sum_256(sy, smem);
    float bz = block_sum_256(sz, smem);
    if (threadIdx.x == 0) {
        atomicAdd(&sums[0], bx);
        atomicAdd(&sums[1], by);
        atomicAdd(&sums[2], bz);
    }
}

// transform + project + scatter-min depth.
// LDS hash (linear probing) dedups intra-block duplicates; COHERENT
// test-before-atomic (agent-scope load, sees past stale per-XCD L2)
// kills cross-block same-address serialization on border pixels.
#define TSIZE 1024
__global__ void k_project(const float* __restrict__ verts,
                          const float* __restrict__ quat,
                          const float* __restrict__ trans,
                          const float* __restrict__ intr,
                          const float* __restrict__ extr,
                          const float* __restrict__ sums,
                          unsigned* __restrict__ depth_bits) {
    __shared__ unsigned h_key[TSIZE];
    __shared__ unsigned h_val[TSIZE];
    for (int s = threadIdx.x; s < TSIZE; s += blockDim.x) {
        h_key[s] = 0xFFFFFFFFu;
        h_val[s] = 0xFFFFFFFFu;
    }
    __syncthreads();

    int j = blockIdx.x * blockDim.x + threadIdx.x;
    if (j < NV) {
        float qx = quat[0], qy = quat[1], qz = quat[2], qw = quat[3];
        float qn = rsqrtf(qx * qx + qy * qy + qz * qz + qw * qw);
        qx *= qn; qy *= qn; qz *= qn; qw *= qn;

        const float inv_nv = 1.0f / (float)NV;
        float mx = sums[0] * inv_nv, my = sums[1] * inv_nv, mz = sums[2] * inv_nv;

        float vx = verts[3 * j + 0] - mx;
        float vy = verts[3 * j + 1] - my;
        float vz = verts[3 * j + 2] - mz;

        float uvx = qy * vz - qz * vy;
        float uvy = qz * vx - qx * vz;
        float uvz = qx * vy - qy * vx;
        float uuvx = qy * uvz - qz * uvy;
        float uuvy = qz * uvx - qx * uvz;
        float uuvz = qx * uvy - qy * uvx;
        float tx = vx + 2.f * (qw * uvx + uuvx) + trans[0];
        float ty = vy + 2.f * (qw * uvy + uuvy) + trans[1];
        float tz = vz + 2.f * (qw * uvz + uuvz) + trans[2];

        float px = extr[0] * tx + extr[1] * ty + extr[2]  * tz + extr[3];
        float py = extr[4] * tx + extr[5] * ty + extr[6]  * tz + extr[7];
        float pz = extr[8] * tx + extr[9] * ty + extr[10] * tz + extr[11];

        float pr0 = intr[0] * px + intr[1] * py + intr[2] * pz;
        float pr1 = intr[3] * px + intr[4] * py + intr[5] * pz;
        float pr2 = intr[6] * px + intr[7] * py + intr[8] * pz;

        float u = pr0 / pr2;
        float v = pr1 / pr2;
        float xf = fminf(fmaxf(rintf(u), 0.f), (float)(W_IMG - 1));
        float yf = fminf(fmaxf(rintf(v), 0.f), (float)(H_IMG - 1));
        unsigned flat = (unsigned)((int)yf * W_IMG + (int)xf);

        if (pz > 0.f) {
            unsigned zbits = __float_as_uint(pz);  // positive floats order as uints
            unsigned slot = (flat * 2654435761u) >> 22;  // top 10 bits
            bool done = false;
#pragma unroll
            for (int p = 0; p < 8; ++p) {
                unsigned old = atomicCAS(&h_key[slot], 0xFFFFFFFFu, flat);
                if (old == 0xFFFFFFFFu || old == flat) {
                    atomicMin(&h_val[slot], zbits);   // aggregate in LDS
                    done = true;
                    break;
                }
                slot = (slot + 1) & (TSIZE - 1);      // linear probe
            }
            if (!done) {
                unsigned cur = __hip_atomic_load(&depth_bits[flat],
                                                 __ATOMIC_RELAXED,
                                                 __HIP_MEMORY_SCOPE_AGENT);
                if (zbits < cur) atomicMin(&depth_bits[flat], zbits);
            }
        }
    }
    __syncthreads();
    for (int s = threadIdx.x; s < TSIZE; s += blockDim.x) {
        unsigned k = h_key[s];
        if (k != 0xFFFFFFFFu) {
            unsigned v = h_val[s];
            unsigned cur = __hip_atomic_load(&depth_bits[k],
                                             __ATOMIC_RELAXED,
                                             __HIP_MEMORY_SCOPE_AGENT);
            if (v < cur) atomicMin(&depth_bits[k], v);  // coherent filter
        }
    }
}

// edge scatter: ONE u64 atomic per edge (packed x|y|z|cnt)
__global__ void k_edges(const int4* __restrict__ edges2,
                        const unsigned long long* __restrict__ pdv,
                        unsigned long long* __restrict__ neigh) {
    int t = blockIdx.x * blockDim.x + threadIdx.x;
    if (t >= NE / 2) return;
    int4 e = edges2[t];
    unsigned long long p0 = pdv[e.y];
    unsigned long long p1 = pdv[e.w];
    atomicAdd(&neigh[(size_t)e.x], p0);
    atomicAdd(&neigh[(size_t)e.z], p1);
}

// e_data = sum((clip(depth,0,10) - hand)^2)
__global__ void k_edata(const unsigned* __restrict__ depth_bits,
                        const float* __restrict__ hand, float* out) {
    __shared__ float smem[4];
    int i = blockIdx.x * blockDim.x + threadIdx.x;
    int stride = gridDim.x * blockDim.x;
    float acc = 0.f;
    for (int j = i; j < HW_IMG; j += stride) {
        float depth = fminf(fmaxf(__uint_as_float(depth_bits[j]), 0.f), MAX_DEPTH);
        float diff = depth - hand[j];
        acc += diff * diff;
    }
    float b = block_sum_256(acc, smem);
    if (threadIdx.x == 0) atomicAdd(out, b);
}

// e_rigid = CREGU * sum(|| deg*dv - neigh ||^2)
__global__ void k_erigid(const float* __restrict__ verts,
                         const float* __restrict__ verts_ref,
                         const unsigned long long* __restrict__ neigh,
                         float* out) {
    __shared__ float smem[4];
    int i = blockIdx.x * blockDim.x + threadIdx.x;
    int stride = gridDim.x * blockDim.x;
    float acc = 0.f;
    for (int j = i; j < NV; j += stride) {
        unsigned long long n = neigh[j];
        int cnt = (int)(n & 63ull);
        int rz  = (int)((n >> 6)  & 0x3FFFFull);
        int ry  = (int)((n >> 24) & 0xFFFFFull);
        int rx  = (int)(n >> 44);
        float nx = (float)(rx - cnt * BXY) * INV_SXY;
        float ny = (float)(ry - cnt * BXY) * INV_SXY;
        float nz = (float)(rz - cnt * BZ)  * INV_SZ;
        float dg = (float)cnt;
        float dx = verts[3 * j + 0] - verts_ref[3 * j + 0];
        float dy = verts[3 * j + 1] - verts_ref[3 * j + 1];
        float dz = verts[3 * j + 2] - verts_ref[3 * j + 2];
        float lx = dg * dx - nx;
        float ly = dg * dy - ny;
        float lz = dg * dz - nz;
        acc += lx * lx + ly * ly + lz * lz;
    }
    float b = block_sum_256(acc, smem);
    if (threadIdx.x == 0) atomicAdd(out, CREGU * b);
}

extern "C" void kernel_launch(void* const* d_in, const int* in_sizes, int n_in,
                              void* d_out, int out_size, void* d_ws, size_t ws_size,
                              hipStream_t stream) {
    const float* verts     = (const float*)d_in[0];
    const float* verts_ref = (const float*)d_in[1];
    const float* quat      = (const float*)d_in[2];
    const float* trans     = (const float*)d_in[3];
    const float* hand      = (const float*)d_in[4];
    const float* intr      = (const float*)d_in[5];
    const float* extr      = (const float*)d_in[6];
    const int*   edges     = (const int*)d_in[7];
    float* out = (float*)d_out;

    char* ws = (char*)d_ws;
    unsigned*           depth_bits = (unsigned*)ws;
    unsigned long long* pdv        = (unsigned long long*)(ws + (size_t)HW_IMG * 4);
    unsigned long long* neigh      = (unsigned long long*)(ws + (size_t)HW_IMG * 4 + (size_t)NV * 8);
    float*              sums       = (float*)(ws + (size_t)HW_IMG * 4 + (size_t)NV * 16);

    const int B = 256;

    k_init<<<2048, B, 0, stream>>>(depth_bits, neigh, sums, out);
    k_sum_dv<<<1024, B, 0, stream>>>(verts, verts_ref, pdv, sums);
    k_project<<<(NV + B - 1) / B, B, 0, stream>>>(verts, quat, trans, intr, extr,
                                                  sums, depth_bits);
    k_edges<<<((NE / 2) + B - 1) / B, B, 0, stream>>>((const int4*)edges, pdv, neigh);
    k_edata<<<1024, B, 0, stream>>>(depth_bits, hand, out);
    k_erigid<<<1024, B, 0, stream>>>(verts, verts_ref, neigh, out);
}

// Round 6
// 384.022 us; speedup vs baseline: 1.0764x; 1.0764x over previous
//
#include <hip/hip_runtime.h>

#define W_IMG 1024
#define H_IMG 1024
#define HW_IMG (W_IMG * H_IMG)
#define NV 1000000
#define NE 3000000
#define MAX_DEPTH 10.0f
#define CREGU 2000.0f

// ---- single-u64-per-edge fixed-point packing ----
// layout (LSB..MSB): cnt:6 | z:18 | y:20 | x:20
#define SXY 65536.0f
#define INV_SXY 1.52587890625e-5f
#define SZ 16384.0f
#define INV_SZ 6.103515625e-5f
#define BXY 8192
#define BZ 2048

__device__ __forceinline__ unsigned long long pack_dv(float x, float y, float z) {
    x = fminf(fmaxf(x, -0.12f), 0.12f);
    y = fminf(fmaxf(y, -0.12f), 0.12f);
    z = fminf(fmaxf(z, -0.12f), 0.12f);
    unsigned long long px = (unsigned)((int)rintf(x * SXY) + BXY);
    unsigned long long py = (unsigned)((int)rintf(y * SXY) + BXY);
    unsigned long long pz = (unsigned)((int)rintf(z * SZ) + BZ);
    return (px << 44) | (py << 24) | (pz << 6) | 1ull;
}

__device__ __forceinline__ float block_sum_256(float v, float* smem) {
#pragma unroll
    for (int o = 32; o > 0; o >>= 1) v += __shfl_down(v, o, 64);
    int lane = threadIdx.x & 63;
    int wid  = threadIdx.x >> 6;
    if (lane == 0) smem[wid] = v;
    __syncthreads();
    float r = 0.f;
    if (threadIdx.x == 0) r = smem[0] + smem[1] + smem[2] + smem[3];
    __syncthreads();
    return r;  // valid on thread 0 only
}

__global__ void k_init(unsigned* depth_bits, int ncopy,
                       unsigned long long* neigh, float* sums, float* out) {
    int i = blockIdx.x * blockDim.x + threadIdx.x;
    int stride = gridDim.x * blockDim.x;
    int tot = ncopy * HW_IMG;
    for (int j = i; j < tot; j += stride) depth_bits[j] = 0x41200000u;  // 10.0f
    for (int j = i; j < NV; j += stride) neigh[j] = 0ull;
    if (i == 0) {
        sums[0] = 0.f; sums[1] = 0.f; sums[2] = 0.f;
        out[0] = 0.f;
    }
}

// vertex sums (for mean) + packed dv
__global__ void k_sum_dv(const float* __restrict__ verts,
                         const float* __restrict__ verts_ref,
                         unsigned long long* __restrict__ pdv, float* sums) {
    __shared__ float smem[4];
    int i = blockIdx.x * blockDim.x + threadIdx.x;
    int stride = gridDim.x * blockDim.x;
    float sx = 0.f, sy = 0.f, sz = 0.f;
    for (int j = i; j < NV; j += stride) {
        float x = verts[3 * j + 0];
        float y = verts[3 * j + 1];
        float z = verts[3 * j + 2];
        sx += x; sy += y; sz += z;
        pdv[j] = pack_dv(x - verts_ref[3 * j + 0],
                         y - verts_ref[3 * j + 1],
                         z - verts_ref[3 * j + 2]);
    }
    float bx = block_sum_256(sx, smem);
    float by = block_sum_256(sy, smem);
    float bz = block_sum_256(sz, smem);
    if (threadIdx.x == 0) {
        atomicAdd(&sums[0], bx);
        atomicAdd(&sums[1], by);
        atomicAdd(&sums[2], bz);
    }
}

// transform + project + scatter-min depth.
// Grid-stride (1024 blocks, ~4 verts/thread) + per-block LDS hash with
// 4-probe linear probing dedups intra-block duplicates; flush targets one
// of ncopy PRIVATE depth copies (blockIdx & (ncopy-1)) to split the
// same-address serialization chains on border pixels.
#define TSIZE 2048
#define PROJ_BLOCKS 1024
__global__ void k_project(const float* __restrict__ verts,
                          const float* __restrict__ quat,
                          const float* __restrict__ trans,
                          const float* __restrict__ intr,
                          const float* __restrict__ extr,
                          const float* __restrict__ sums,
                          unsigned* __restrict__ depth_bits, int ncopy) {
    __shared__ unsigned h_key[TSIZE];
    __shared__ unsigned h_val[TSIZE];
    for (int s = threadIdx.x; s < TSIZE; s += blockDim.x) {
        h_key[s] = 0xFFFFFFFFu;
        h_val[s] = 0xFFFFFFFFu;
    }
    __syncthreads();

    unsigned* __restrict__ db =
        depth_bits + (size_t)(blockIdx.x & (ncopy - 1)) * HW_IMG;

    float qx = quat[0], qy = quat[1], qz = quat[2], qw = quat[3];
    float qn = rsqrtf(qx * qx + qy * qy + qz * qz + qw * qw);
    qx *= qn; qy *= qn; qz *= qn; qw *= qn;

    const float inv_nv = 1.0f / (float)NV;
    float mx = sums[0] * inv_nv, my = sums[1] * inv_nv, mz = sums[2] * inv_nv;
    float t0 = trans[0], t1 = trans[1], t2 = trans[2];
    float e0 = extr[0], e1 = extr[1], e2 = extr[2],  e3 = extr[3];
    float e4 = extr[4], e5 = extr[5], e6 = extr[6],  e7 = extr[7];
    float e8 = extr[8], e9 = extr[9], e10 = extr[10], e11 = extr[11];
    float i0 = intr[0], i1 = intr[1], i2 = intr[2];
    float i3 = intr[3], i4 = intr[4], i5 = intr[5];
    float i6 = intr[6], i7 = intr[7], i8 = intr[8];

    int stride = gridDim.x * blockDim.x;
    for (int j = blockIdx.x * blockDim.x + threadIdx.x; j < NV; j += stride) {
        float vx = verts[3 * j + 0] - mx;
        float vy = verts[3 * j + 1] - my;
        float vz = verts[3 * j + 2] - mz;

        float uvx = qy * vz - qz * vy;
        float uvy = qz * vx - qx * vz;
        float uvz = qx * vy - qy * vx;
        float uuvx = qy * uvz - qz * uvy;
        float uuvy = qz * uvx - qx * uvz;
        float uuvz = qx * uvy - qy * uvx;
        float tx = vx + 2.f * (qw * uvx + uuvx) + t0;
        float ty = vy + 2.f * (qw * uvy + uuvy) + t1;
        float tz = vz + 2.f * (qw * uvz + uuvz) + t2;

        float px = e0 * tx + e1 * ty + e2  * tz + e3;
        float py = e4 * tx + e5 * ty + e6  * tz + e7;
        float pz = e8 * tx + e9 * ty + e10 * tz + e11;

        float pr0 = i0 * px + i1 * py + i2 * pz;
        float pr1 = i3 * px + i4 * py + i5 * pz;
        float pr2 = i6 * px + i7 * py + i8 * pz;

        float u = pr0 / pr2;
        float v = pr1 / pr2;
        float xf = fminf(fmaxf(rintf(u), 0.f), (float)(W_IMG - 1));
        float yf = fminf(fmaxf(rintf(v), 0.f), (float)(H_IMG - 1));
        unsigned flat = (unsigned)((int)yf * W_IMG + (int)xf);

        if (pz > 0.f) {
            unsigned zbits = __float_as_uint(pz);  // positive floats order as uints
            unsigned slot = (flat * 2654435761u) >> 21;  // top 11 bits
            bool done = false;
#pragma unroll
            for (int p = 0; p < 4; ++p) {
                unsigned old = atomicCAS(&h_key[slot], 0xFFFFFFFFu, flat);
                if (old == 0xFFFFFFFFu || old == flat) {
                    atomicMin(&h_val[slot], zbits);   // aggregate in LDS
                    done = true;
                    break;
                }
                slot = (slot + 1) & (TSIZE - 1);
            }
            if (!done) {
                if (zbits < db[flat]) atomicMin(&db[flat], zbits);
            }
        }
    }
    __syncthreads();
    for (int s = threadIdx.x; s < TSIZE; s += blockDim.x) {
        unsigned k = h_key[s];
        if (k != 0xFFFFFFFFu) {
            unsigned v = h_val[s];
            if (v < db[k]) atomicMin(&db[k], v);
        }
    }
}

// edge scatter: ONE u64 atomic per edge (packed x|y|z|cnt)
__global__ void k_edges(const int4* __restrict__ edges2,
                        const unsigned long long* __restrict__ pdv,
                        unsigned long long* __restrict__ neigh) {
    int t = blockIdx.x * blockDim.x + threadIdx.x;
    if (t >= NE / 2) return;
    int4 e = edges2[t];
    unsigned long long p0 = pdv[e.y];
    unsigned long long p1 = pdv[e.w];
    atomicAdd(&neigh[(size_t)e.x], p0);
    atomicAdd(&neigh[(size_t)e.z], p1);
}

// e_data = sum((clip(min over copies, 0, 10) - hand)^2)
__global__ void k_edata(const unsigned* __restrict__ depth_bits, int ncopy,
                        const float* __restrict__ hand, float* out) {
    __shared__ float smem[4];
    int i = blockIdx.x * blockDim.x + threadIdx.x;
    int stride = gridDim.x * blockDim.x;
    float acc = 0.f;
    for (int j = i; j < HW_IMG; j += stride) {
        float dmin = __uint_as_float(depth_bits[j]);
        for (int c = 1; c < ncopy; ++c)
            dmin = fminf(dmin, __uint_as_float(depth_bits[(size_t)c * HW_IMG + j]));
        float depth = fminf(fmaxf(dmin, 0.f), MAX_DEPTH);
        float diff = depth - hand[j];
        acc += diff * diff;
    }
    float b = block_sum_256(acc, smem);
    if (threadIdx.x == 0) atomicAdd(out, b);
}

// e_rigid = CREGU * sum(|| deg*dv - neigh ||^2)
__global__ void k_erigid(const float* __restrict__ verts,
                         const float* __restrict__ verts_ref,
                         const unsigned long long* __restrict__ neigh,
                         float* out) {
    __shared__ float smem[4];
    int i = blockIdx.x * blockDim.x + threadIdx.x;
    int stride = gridDim.x * blockDim.x;
    float acc = 0.f;
    for (int j = i; j < NV; j += stride) {
        unsigned long long n = neigh[j];
        int cnt = (int)(n & 63ull);
        int rz  = (int)((n >> 6)  & 0x3FFFFull);
        int ry  = (int)((n >> 24) & 0xFFFFFull);
        int rx  = (int)(n >> 44);
        float nx = (float)(rx - cnt * BXY) * INV_SXY;
        float ny = (float)(ry - cnt * BXY) * INV_SXY;
        float nz = (float)(rz - cnt * BZ)  * INV_SZ;
        float dg = (float)cnt;
        float dx = verts[3 * j + 0] - verts_ref[3 * j + 0];
        float dy = verts[3 * j + 1] - verts_ref[3 * j + 1];
        float dz = verts[3 * j + 2] - verts_ref[3 * j + 2];
        float lx = dg * dx - nx;
        float ly = dg * dy - ny;
        float lz = dg * dz - nz;
        acc += lx * lx + ly * ly + lz * lz;
    }
    float b = block_sum_256(acc, smem);
    if (threadIdx.x == 0) atomicAdd(out, CREGU * b);
}

extern "C" void kernel_launch(void* const* d_in, const int* in_sizes, int n_in,
                              void* d_out, int out_size, void* d_ws, size_t ws_size,
                              hipStream_t stream) {
    const float* verts     = (const float*)d_in[0];
    const float* verts_ref = (const float*)d_in[1];
    const float* quat      = (const float*)d_in[2];
    const float* trans     = (const float*)d_in[3];
    const float* hand      = (const float*)d_in[4];
    const float* intr      = (const float*)d_in[5];
    const float* extr      = (const float*)d_in[6];
    const int*   edges     = (const int*)d_in[7];
    float* out = (float*)d_out;

    // choose 4 private depth copies if workspace allows, else 2
    size_t need4 = (size_t)4 * HW_IMG * 4 + (size_t)NV * 16 + 16;
    int ncopy = (ws_size >= need4) ? 4 : 2;

    char* ws = (char*)d_ws;
    unsigned*           depth_bits = (unsigned*)ws;
    unsigned long long* pdv        = (unsigned long long*)(ws + (size_t)ncopy * HW_IMG * 4);
    unsigned long long* neigh      = pdv + NV;
    float*              sums       = (float*)(neigh + NV);

    const int B = 256;

    k_init<<<2048, B, 0, stream>>>(depth_bits, ncopy, neigh, sums, out);
    k_sum_dv<<<1024, B, 0, stream>>>(verts, verts_ref, pdv, sums);
    k_project<<<PROJ_BLOCKS, B, 0, stream>>>(verts, quat, trans, intr, extr,
                                             sums, depth_bits, ncopy);
    k_edges<<<((NE / 2) + B - 1) / B, B, 0, stream>>>((const int4*)edges, pdv, neigh);
    k_edata<<<1024, B, 0, stream>>>(depth_bits, ncopy, hand, out);
    k_erigid<<<1024, B, 0, stream>>>(verts, verts_ref, neigh, out);
}

// Round 7
// 343.136 us; speedup vs baseline: 1.2047x; 1.1192x over previous
//
#include <hip/hip_runtime.h>

#define W_IMG 1024
#define H_IMG 1024
#define HW_IMG (W_IMG * H_IMG)
#define NV 1000000
#define NE 3000000
#define MAX_DEPTH 10.0f
#define CREGU 2000.0f

// ---- single-u64-per-edge fixed-point packing ----
// layout (LSB..MSB): cnt:6 | z:18 | y:20 | x:20
#define SXY 65536.0f
#define INV_SXY 1.52587890625e-5f
#define SZ 16384.0f
#define INV_SZ 6.103515625e-5f
#define BXY 8192
#define BZ 2048

#define PREP_BLOCKS 2048
#define GEO_BLOCKS 1024
#define EDGE_BLOCKS ((NE / 2 + 255) / 256)   // 5860
#define TSIZE 2048

__device__ __forceinline__ unsigned long long pack_dv(float x, float y, float z) {
    x = fminf(fmaxf(x, -0.12f), 0.12f);
    y = fminf(fmaxf(y, -0.12f), 0.12f);
    z = fminf(fmaxf(z, -0.12f), 0.12f);
    unsigned long long px = (unsigned)((int)rintf(x * SXY) + BXY);
    unsigned long long py = (unsigned)((int)rintf(y * SXY) + BXY);
    unsigned long long pz = (unsigned)((int)rintf(z * SZ) + BZ);
    return (px << 44) | (py << 24) | (pz << 6) | 1ull;
}

__device__ __forceinline__ float block_sum_256(float v, float* smem) {
#pragma unroll
    for (int o = 32; o > 0; o >>= 1) v += __shfl_down(v, o, 64);
    int lane = threadIdx.x & 63;
    int wid  = threadIdx.x >> 6;
    if (lane == 0) smem[wid] = v;
    __syncthreads();
    float r = 0.f;
    if (threadIdx.x == 0) r = smem[0] + smem[1] + smem[2] + smem[3];
    __syncthreads();
    return r;  // valid on thread 0 only
}

// K1: all initialization + pdv + per-block partial vertex sums (no atomics)
__global__ void k_prep(const float* __restrict__ verts,
                       const float* __restrict__ verts_ref,
                       unsigned long long* __restrict__ pdv,
                       unsigned* __restrict__ depth_bits, int ncopy,
                       unsigned long long* __restrict__ neigh,
                       float4* __restrict__ partial, float* out) {
    __shared__ float smem[4];
    int i = blockIdx.x * blockDim.x + threadIdx.x;
    int stride = gridDim.x * blockDim.x;

    float sx = 0.f, sy = 0.f, sz = 0.f;
    for (int j = i; j < NV; j += stride) {
        float x = verts[3 * j + 0];
        float y = verts[3 * j + 1];
        float z = verts[3 * j + 2];
        sx += x; sy += y; sz += z;
        pdv[j] = pack_dv(x - verts_ref[3 * j + 0],
                         y - verts_ref[3 * j + 1],
                         z - verts_ref[3 * j + 2]);
        neigh[j] = 0ull;
    }
    int tot = ncopy * HW_IMG;
    for (int j = i; j < tot; j += stride) depth_bits[j] = 0x41200000u;  // 10.0f
    if (i == 0) out[0] = 0.f;

    float bx = block_sum_256(sx, smem);
    float by = block_sum_256(sy, smem);
    float bz = block_sum_256(sz, smem);
    if (threadIdx.x == 0) {
        float4 p; p.x = bx; p.y = by; p.z = bz; p.w = 0.f;
        partial[blockIdx.x] = p;
    }
}

// K2: block-range split — edge scatter (atomic-rate bound, ~0.4% VALU) and
// projection/depth scatter (VALU+LDS bound) run concurrently on different CUs,
// overlapping geo's compute under the edges' fabric-atomic shadow.
__global__ void k_main(const int4* __restrict__ edges2,
                       const unsigned long long* __restrict__ pdv,
                       unsigned long long* __restrict__ neigh,
                       const float* __restrict__ verts,
                       const float* __restrict__ quat,
                       const float* __restrict__ trans,
                       const float* __restrict__ intr,
                       const float* __restrict__ extr,
                       const float4* __restrict__ partial,
                       unsigned* __restrict__ depth_bits, int ncopy) {
    __shared__ unsigned h_key[TSIZE];
    __shared__ unsigned h_val[TSIZE];
    __shared__ float rsm[8];

    if (blockIdx.x < EDGE_BLOCKS) {
        // ---------------- edge scatter: one u64 atomic per edge ----------------
        int t = blockIdx.x * blockDim.x + threadIdx.x;
        if (t < NE / 2) {
            int4 e = edges2[t];
            unsigned long long p0 = pdv[e.y];
            unsigned long long p1 = pdv[e.w];
            atomicAdd(&neigh[(size_t)e.x], p0);
            atomicAdd(&neigh[(size_t)e.z], p1);
        }
        return;
    }

    // ---------------- projection + depth scatter-min ----------------
    int gb = blockIdx.x - EDGE_BLOCKS;  // 0..GEO_BLOCKS-1
    for (int s = threadIdx.x; s < TSIZE; s += blockDim.x) {
        h_key[s] = 0xFFFFFFFFu;
        h_val[s] = 0xFFFFFFFFu;
    }
    __syncthreads();

    // reduce partial sums -> mean (PREP_BLOCKS entries)
    float sx = 0.f, sy = 0.f, sz = 0.f;
    for (int p = threadIdx.x; p < PREP_BLOCKS; p += blockDim.x) {
        float4 v = partial[p];
        sx += v.x; sy += v.y; sz += v.z;
    }
    float bx = block_sum_256(sx, rsm);
    float by = block_sum_256(sy, rsm);
    float bz = block_sum_256(sz, rsm);
    if (threadIdx.x == 0) {
        const float inv_nv = 1.0f / (float)NV;
        rsm[4] = bx * inv_nv; rsm[5] = by * inv_nv; rsm[6] = bz * inv_nv;
    }
    __syncthreads();
    float mx = rsm[4], my = rsm[5], mz = rsm[6];

    float qx = quat[0], qy = quat[1], qz = quat[2], qw = quat[3];
    float qn = rsqrtf(qx * qx + qy * qy + qz * qz + qw * qw);
    qx *= qn; qy *= qn; qz *= qn; qw *= qn;
    float t0 = trans[0], t1 = trans[1], t2 = trans[2];
    float e0 = extr[0], e1 = extr[1], e2 = extr[2],  e3 = extr[3];
    float e4 = extr[4], e5 = extr[5], e6 = extr[6],  e7 = extr[7];
    float e8 = extr[8], e9 = extr[9], e10 = extr[10], e11 = extr[11];
    float i0 = intr[0], i1 = intr[1], i2 = intr[2];
    float i3 = intr[3], i4 = intr[4], i5 = intr[5];
    float i6 = intr[6], i7 = intr[7], i8 = intr[8];

    unsigned* __restrict__ db =
        depth_bits + (size_t)(gb & (ncopy - 1)) * HW_IMG;

    int stride = GEO_BLOCKS * blockDim.x;
    for (int j = gb * blockDim.x + threadIdx.x; j < NV; j += stride) {
        float vx = verts[3 * j + 0] - mx;
        float vy = verts[3 * j + 1] - my;
        float vz = verts[3 * j + 2] - mz;

        float uvx = qy * vz - qz * vy;
        float uvy = qz * vx - qx * vz;
        float uvz = qx * vy - qy * vx;
        float uuvx = qy * uvz - qz * uvy;
        float uuvy = qz * uvx - qx * uvz;
        float uuvz = qx * uvy - qy * uvx;
        float tx = vx + 2.f * (qw * uvx + uuvx) + t0;
        float ty = vy + 2.f * (qw * uvy + uuvy) + t1;
        float tz = vz + 2.f * (qw * uvz + uuvz) + t2;

        float px = e0 * tx + e1 * ty + e2  * tz + e3;
        float py = e4 * tx + e5 * ty + e6  * tz + e7;
        float pz = e8 * tx + e9 * ty + e10 * tz + e11;

        float pr0 = i0 * px + i1 * py + i2 * pz;
        float pr1 = i3 * px + i4 * py + i5 * pz;
        float pr2 = i6 * px + i7 * py + i8 * pz;

        float u = pr0 / pr2;
        float v = pr1 / pr2;
        float ru = rintf(u);
        float rv = rintf(v);
        bool border = (ru < 0.f) | (ru > (float)(W_IMG - 1)) |
                      (rv < 0.f) | (rv > (float)(H_IMG - 1));
        float xf = fminf(fmaxf(ru, 0.f), (float)(W_IMG - 1));
        float yf = fminf(fmaxf(rv, 0.f), (float)(H_IMG - 1));
        unsigned flat = (unsigned)((int)yf * W_IMG + (int)xf);

        if (pz > 0.f) {
            unsigned zbits = __float_as_uint(pz);  // positive floats order as uints
            if (!border) {
                // interior pixels are ~unique: direct, uncontended
                atomicMin(&db[flat], zbits);
            } else {
                // contended border pixels: aggregate in LDS hash
                unsigned slot = (flat * 2654435761u) >> 21;  // top 11 bits
                bool done = false;
#pragma unroll
                for (int p = 0; p < 4; ++p) {
                    unsigned old = atomicCAS(&h_key[slot], 0xFFFFFFFFu, flat);
                    if (old == 0xFFFFFFFFu || old == flat) {
                        atomicMin(&h_val[slot], zbits);
                        done = true;
                        break;
                    }
                    slot = (slot + 1) & (TSIZE - 1);
                }
                if (!done) atomicMin(&db[flat], zbits);
            }
        }
    }
    __syncthreads();
    for (int s = threadIdx.x; s < TSIZE; s += blockDim.x) {
        unsigned k = h_key[s];
        if (k != 0xFFFFFFFFu) atomicMin(&db[k], h_val[s]);
    }
}

// K3: e_data (blocks 0..EDATA_BLOCKS-1) + e_rigid (rest), both -> out[0]
#define EDATA_BLOCKS 256
#define ENERGY_BLOCKS 1024
__global__ void k_energy(const unsigned* __restrict__ depth_bits, int ncopy,
                         const float* __restrict__ hand,
                         const float* __restrict__ verts,
                         const float* __restrict__ verts_ref,
                         const unsigned long long* __restrict__ neigh,
                         float* out) {
    __shared__ float smem[4];
    if (blockIdx.x < EDATA_BLOCKS) {
        int i = blockIdx.x * blockDim.x + threadIdx.x;
        int stride = EDATA_BLOCKS * blockDim.x;
        float acc = 0.f;
        for (int j = i; j < HW_IMG; j += stride) {
            float dmin = __uint_as_float(depth_bits[j]);
            for (int c = 1; c < ncopy; ++c)
                dmin = fminf(dmin, __uint_as_float(depth_bits[(size_t)c * HW_IMG + j]));
            float depth = fminf(fmaxf(dmin, 0.f), MAX_DEPTH);
            float diff = depth - hand[j];
            acc += diff * diff;
        }
        float b = block_sum_256(acc, smem);
        if (threadIdx.x == 0) atomicAdd(out, b);
    } else {
        int gb = blockIdx.x - EDATA_BLOCKS;
        int nb = ENERGY_BLOCKS - EDATA_BLOCKS;
        int i = gb * blockDim.x + threadIdx.x;
        int stride = nb * blockDim.x;
        float acc = 0.f;
        for (int j = i; j < NV; j += stride) {
            unsigned long long n = neigh[j];
            int cnt = (int)(n & 63ull);
            int rz  = (int)((n >> 6)  & 0x3FFFFull);
            int ry  = (int)((n >> 24) & 0xFFFFFull);
            int rx  = (int)(n >> 44);
            float nx = (float)(rx - cnt * BXY) * INV_SXY;
            float ny = (float)(ry - cnt * BXY) * INV_SXY;
            float nz = (float)(rz - cnt * BZ)  * INV_SZ;
            float dg = (float)cnt;
            float dx = verts[3 * j + 0] - verts_ref[3 * j + 0];
            float dy = verts[3 * j + 1] - verts_ref[3 * j + 1];
            float dz = verts[3 * j + 2] - verts_ref[3 * j + 2];
            float lx = dg * dx - nx;
            float ly = dg * dy - ny;
            float lz = dg * dz - nz;
            acc += lx * lx + ly * ly + lz * lz;
        }
        float b = block_sum_256(acc, smem);
        if (threadIdx.x == 0) atomicAdd(out, CREGU * b);
    }
}

extern "C" void kernel_launch(void* const* d_in, const int* in_sizes, int n_in,
                              void* d_out, int out_size, void* d_ws, size_t ws_size,
                              hipStream_t stream) {
    const float* verts     = (const float*)d_in[0];
    const float* verts_ref = (const float*)d_in[1];
    const float* quat      = (const float*)d_in[2];
    const float* trans     = (const float*)d_in[3];
    const float* hand      = (const float*)d_in[4];
    const float* intr      = (const float*)d_in[5];
    const float* extr      = (const float*)d_in[6];
    const int*   edges     = (const int*)d_in[7];
    float* out = (float*)d_out;

    // choose private depth copy count per workspace size
    size_t fixed = (size_t)NV * 16 + (size_t)PREP_BLOCKS * 16 + 256;
    int ncopy = (ws_size >= (size_t)4 * HW_IMG * 4 + fixed) ? 4
              : (ws_size >= (size_t)2 * HW_IMG * 4 + fixed) ? 2 : 1;

    char* ws = (char*)d_ws;
    unsigned*           depth_bits = (unsigned*)ws;
    unsigned long long* pdv        = (unsigned long long*)(ws + (size_t)ncopy * HW_IMG * 4);
    unsigned long long* neigh      = pdv + NV;
    float4*             partial    = (float4*)(neigh + NV);

    const int B = 256;

    k_prep<<<PREP_BLOCKS, B, 0, stream>>>(verts, verts_ref, pdv, depth_bits,
                                          ncopy, neigh, partial, out);
    k_main<<<EDGE_BLOCKS + GEO_BLOCKS, B, 0, stream>>>(
        (const int4*)edges, pdv, neigh, verts, quat, trans, intr, extr,
        partial, depth_bits, ncopy);
    k_energy<<<ENERGY_BLOCKS, B, 0, stream>>>(depth_bits, ncopy, hand,
                                              verts, verts_ref, neigh, out);
}